// Round 4
// baseline (534.122 us; speedup 1.0000x reference)
//
#include <hip/hip_runtime.h>

#define J 10
#define P 16384
#define D 8
#define O 16
#define B 32

#define WPB 4                 // waves per block
#define SP 8                  // p's per wave
#define PT (WPB * SP)         // 32 p per block
#define GX (P / PT)           // 512
#define BG 4                  // b-groups (8 b each)
#define SJO (B * J * O)       // 5120

// ---- DPP cross-lane helpers ----
template <int CTRL>
__device__ __forceinline__ float dpp_mov_f(float v) {
    return __int_as_float(__builtin_amdgcn_update_dpp(
        0, __float_as_int(v), CTRL, 0xF, 0xF, true));
}
// sum across a 16-lane row; result broadcast to all 16 lanes
__device__ __forceinline__ float row_sum16(float v) {
    v += dpp_mov_f<0xB1>(v);   // quad_perm xor 1
    v += dpp_mov_f<0x4E>(v);   // quad_perm xor 2
    v += dpp_mov_f<0x124>(v);  // row_ror:4
    v += dpp_mov_f<0x128>(v);  // row_ror:8
    return v;
}

__device__ __forceinline__ unsigned bf16_rne(float f) {
    unsigned u = __float_as_uint(f);
    return (u + 0x7fffu + ((u >> 16) & 1u)) >> 16;
}
__device__ __forceinline__ float bf_lo(unsigned u) { return __uint_as_float(u << 16); }
__device__ __forceinline__ float bf_hi(unsigned u) { return __uint_as_float(u & 0xffff0000u); }

// One-time: W fp32 [j][p][d][o] -> Wt bf16 [j][p][o][d] (16 B per (j,p,o) = one uint4).
// Runs every launch (ws is re-poisoned); W is constant so result is identical.
__global__ __launch_bounds__(256) void conv_w(const float* __restrict__ W,
                                              uint4* __restrict__ Wt)
{
    const int t = blockIdx.x * 256 + threadIdx.x;   // exact: J*P*O threads
    const int o = t & 15;
    const int rest = t >> 4;
    const int p = rest & (P - 1);
    const int j = rest >> 14;
    const float* src = W + ((size_t)(j * P + p) * D) * O + o;
    unsigned bb[D];
#pragma unroll
    for (int d = 0; d < D; ++d) bb[d] = bf16_rne(src[d * O]);
    uint4 out;
    out.x = bb[0] | (bb[1] << 16);
    out.y = bb[2] | (bb[3] << 16);
    out.z = bb[4] | (bb[5] << 16);
    out.w = bb[6] | (bb[7] << 16);
    Wt[t] = out;
}

// One routing pass. Grid (GX, BG). Lane = (o:16, psub:2, bsub:2); wave owns SP p's
// processed in chunks of 2 (psub); bc loop x4 covers the bg's 8 b (b = bg*8+bc*2+bsub).
// W read as one dwordx4 (8 bf16 d-values) per (j,p,o) -> 32 distinct addrs/instr.
__global__ __launch_bounds__(256, 3) void caps_pass(
    const float* __restrict__ x, const uint4* __restrict__ Wt,
    const float* __restrict__ Vsum, float* __restrict__ s_acc, int first)
{
    __shared__ float s_blk[WPB][8 * 168];
    const int tid  = threadIdx.x;
    const int o    = tid & 15;
    const int psub = (tid >> 4) & 1;
    const int bsub = (tid >> 5) & 1;
    const int wid  = tid >> 6;
    const int bg   = blockIdx.y;

    // Vsum for this lane's o, packed bf16 (register pressure): vs_pk[bc][j-pair]
    unsigned vs_pk[4][5];
    if (!first) {
#pragma unroll
        for (int bc = 0; bc < 4; ++bc) {
            const int b = bg * 8 + bc * 2 + bsub;
#pragma unroll
            for (int jp = 0; jp < 5; ++jp) {
                unsigned l0 = bf16_rne(Vsum[(b * J + jp * 2 + 0) * O + o]);
                unsigned l1 = bf16_rne(Vsum[(b * J + jp * 2 + 1) * O + o]);
                vs_pk[bc][jp] = l0 | (l1 << 16);
            }
        }
    }

    float acc[4][J];
#pragma unroll
    for (int bc = 0; bc < 4; ++bc)
#pragma unroll
        for (int j = 0; j < J; ++j) acc[bc][j] = 0.f;

    const int p0 = (blockIdx.x * WPB + wid) * SP;

#pragma unroll 1
    for (int ch = 0; ch < SP / 2; ++ch) {
        const int p = p0 + ch * 2 + psub;
        const uint4* Wl = Wt + (size_t)p * 16 + o;   // + j*P*16

        float uh[4][J];
#pragma unroll
        for (int jh = 0; jh < 2; ++jh) {
            float wv[5][D];
#pragma unroll
            for (int j5 = 0; j5 < 5; ++j5) {
                const uint4 wp = Wl[(size_t)(jh * 5 + j5) * ((size_t)P * 16)];
                wv[j5][0] = bf_lo(wp.x); wv[j5][1] = bf_hi(wp.x);
                wv[j5][2] = bf_lo(wp.y); wv[j5][3] = bf_hi(wp.y);
                wv[j5][4] = bf_lo(wp.z); wv[j5][5] = bf_hi(wp.z);
                wv[j5][6] = bf_lo(wp.w); wv[j5][7] = bf_hi(wp.w);
            }
#pragma unroll
            for (int bc = 0; bc < 4; ++bc) {
                const int b = bg * 8 + bc * 2 + bsub;
                const float4* xp = (const float4*)(x + ((size_t)b * P + p) * D);
                const float4 xa = xp[0], xb = xp[1];
                const float xv[8] = {xa.x, xa.y, xa.z, xa.w,
                                     xb.x, xb.y, xb.z, xb.w};
#pragma unroll
                for (int j5 = 0; j5 < 5; ++j5) {
                    float u = 0.f;
#pragma unroll
                    for (int d = 0; d < D; ++d) u = fmaf(xv[d], wv[j5][d], u);
                    uh[bc][jh * 5 + j5] = u;
                }
            }
        }

        if (first) {
            const float cj = 1.0f / (float)J;
#pragma unroll
            for (int bc = 0; bc < 4; ++bc)
#pragma unroll
                for (int j = 0; j < J; ++j)
                    acc[bc][j] = fmaf(cj, uh[bc][j], acc[bc][j]);
        } else {
#pragma unroll
            for (int bc = 0; bc < 4; ++bc) {
                float lg[J];
#pragma unroll
                for (int jp = 0; jp < 5; ++jp) {
                    lg[jp * 2 + 0] = row_sum16(uh[bc][jp * 2 + 0] * bf_lo(vs_pk[bc][jp]));
                    lg[jp * 2 + 1] = row_sum16(uh[bc][jp * 2 + 1] * bf_hi(vs_pk[bc][jp]));
                }
                float mx = lg[0];
#pragma unroll
                for (int j = 1; j < J; ++j) mx = fmaxf(mx, lg[j]);
                float e[J], Z = 0.f;
#pragma unroll
                for (int j = 0; j < J; ++j) { e[j] = __expf(lg[j] - mx); Z += e[j]; }
                const float rZ = __builtin_amdgcn_rcpf(Z);
#pragma unroll
                for (int j = 0; j < J; ++j)
                    acc[bc][j] = fmaf(e[j] * rZ, uh[bc][j], acc[bc][j]);
            }
        }
    }

    // fold the psub pair (lane bit 4): partials over the two p-chains
#pragma unroll
    for (int bc = 0; bc < 4; ++bc)
#pragma unroll
        for (int j = 0; j < J; ++j)
            acc[bc][j] += __shfl_xor(acc[bc][j], 16, 64);

    // per-wave partials -> LDS (psub lanes write same value to same addr: benign)
#pragma unroll
    for (int bc = 0; bc < 4; ++bc) {
        const int bl = bc * 2 + bsub;
#pragma unroll
        for (int j = 0; j < J; ++j)
            s_blk[wid][bl * 168 + j * O + o] = acc[bc][j];
    }
    __syncthreads();

    // cross-wave sum + one atomicAdd per (b,j,o) per block
    for (int i = tid; i < 8 * J * O; i += 256) {
        const int bl = i / (J * O);
        const int r  = i - bl * (J * O);
        const float v = s_blk[0][bl * 168 + r] + s_blk[1][bl * 168 + r]
                      + s_blk[2][bl * 168 + r] + s_blk[3][bl * 168 + r];
        atomicAdd(&s_acc[(bg * 8 + bl) * (J * O) + r], v);
    }
}

// v = squash(s); Vsum += v; zero s_acc for next pass; optionally emit v.
__global__ __launch_bounds__(64) void caps_squash(
    float* __restrict__ s_acc, float* __restrict__ Vsum,
    float* __restrict__ out, int write_out)
{
    const int row = blockIdx.x * 4 + (threadIdx.x >> 4); // 0..B*J-1
    const int o = threadIdx.x & 15;
    float s = s_acc[row * O + o];
    float sq = s * s;
#pragma unroll
    for (int m = 1; m < 16; m <<= 1) sq += __shfl_xor(sq, m, 64);
    const float v = s * (sqrtf(sq) / (1.f + sq));
    Vsum[row * O + o] += v;
    s_acc[row * O + o] = 0.f;
    if (write_out) out[row * O + o] = v;
}

__global__ __launch_bounds__(256) void caps_zero(float* __restrict__ ws)
{
    const int i = blockIdx.x * 256 + threadIdx.x;
    if (i < 2 * SJO) ws[i] = 0.f;   // s_acc + Vsum
}

extern "C" void kernel_launch(void* const* d_in, const int* in_sizes, int n_in,
                              void* d_out, int out_size, void* d_ws, size_t ws_size,
                              hipStream_t stream)
{
    const float* x = (const float*)d_in[0];
    const float* W = (const float*)d_in[1];
    float* out = (float*)d_out;

    uint4* Wt    = (uint4*)d_ws;                                   // J*P*O uint4 = 41.9 MB
    float* s_acc = (float*)((char*)d_ws + (size_t)J * P * O * 16); // SJO floats
    float* Vsum  = s_acc + SJO;                                    // SJO floats

    conv_w<<<dim3(J * P * O / 256), 256, 0, stream>>>(W, Wt);
    caps_zero<<<dim3((2 * SJO + 255) / 256), 256, 0, stream>>>(s_acc);

    for (int it = 0; it < 3; ++it) {
        caps_pass<<<dim3(GX, BG), 256, 0, stream>>>(x, Wt, Vsum, s_acc, it == 0 ? 1 : 0);
        caps_squash<<<dim3(B * J / 4), 64, 0, stream>>>(s_acc, Vsum, out, it == 2 ? 1 : 0);
    }
}

// Round 5
// 388.442 us; speedup vs baseline: 1.3750x; 1.3750x over previous
//
#include <hip/hip_runtime.h>

#define J 10
#define P 16384
#define D 8
#define O 16
#define B 32

#define WPB 4                 // waves per block
#define SP 8                  // p's per wave
#define PT (WPB * SP)         // 32 p per block
#define GXR (P / PT)          // 512 p-ranges
#define BGN 8                 // b-groups (4 b each)
#define NB (GXR * BGN)        // 4096 blocks
#define SJO (B * J * O)       // 5120
#define VSTR 164              // padded per-b LDS stride (160 + 4: bank stagger)

// ---- DPP cross-lane helpers ----
template <int CTRL>
__device__ __forceinline__ float dpp_mov_f(float v) {
    return __int_as_float(__builtin_amdgcn_update_dpp(
        0, __float_as_int(v), CTRL, 0xF, 0xF, true));
}
// sum over lane bits 0-1 (og quad), result in all 4
__device__ __forceinline__ float quad_sum4(float v) {
    v += dpp_mov_f<0xB1>(v);   // quad_perm xor 1
    v += dpp_mov_f<0x4E>(v);   // quad_perm xor 2
    return v;
}
// sum over lane bits 2-3 (psub), og/bsub preserved
__device__ __forceinline__ float psub_sum4(float v) {
    v += dpp_mov_f<0x124>(v);  // row_ror:4
    v += dpp_mov_f<0x128>(v);  // row_ror:8
    return v;
}

// One routing pass. Lane = (og:4 -> o=og*4..og*4+3, psub:4, bsub:4).
// Block owns 32 p's (4 waves x 8) and 4 b's (b = bg*4+bsub). W loads are
// dwordx4 (4 o's) with 16 distinct addrs/instr, straight from pristine d_in.
// XCD swizzle: the 8 bg-blocks sharing a W-slab dispatch consecutively to the
// SAME XCD (blockIdx %8 fixed) -> W-slab (160 KB) served from that XCD's L2.
__global__ __launch_bounds__(256, 2) void caps_pass(
    const float* __restrict__ x, const float* __restrict__ W,
    const float* __restrict__ Vsum, float* __restrict__ s_acc, int first)
{
    __shared__ float vs_s[4 * VSTR];
    __shared__ float s_blk[WPB][4 * VSTR];

    const int tid  = threadIdx.x;
    const int og   = tid & 3;
    const int psub = (tid >> 2) & 3;
    const int bsub = (tid >> 4) & 3;
    const int wid  = tid >> 6;

    const int i  = blockIdx.x;
    const int c  = i & 7;                 // XCD slot
    const int bg = (i >> 3) & 7;          // b-group, cycles fastest per XCD
    const int R  = (i >> 6) * 8 + c;      // p-range 0..511, fixed per 8 consecutive dispatches on one XCD

    const int b = bg * 4 + bsub;

    // stage this block's Vsum slice: vs_s[bl][j*16+o], padded stride
    for (int t = tid; t < 4 * 160; t += 256) {
        const int bl = t / 160, r = t - bl * 160;
        vs_s[bl * VSTR + r] = Vsum[(bg * 4 + bl) * 160 + r];
    }
    __syncthreads();

    float4 acc[J];
#pragma unroll
    for (int j = 0; j < J; ++j) acc[j] = make_float4(0.f, 0.f, 0.f, 0.f);

    const int p0 = R * PT + wid * SP;

#pragma unroll 1
    for (int ch = 0; ch < SP / 4; ++ch) {
        const int p = p0 + ch * 4 + psub;

        const float4* xp = (const float4*)(x + ((size_t)b * P + p) * D);
        const float4 xa = xp[0], xb = xp[1];
        const float xv[8] = {xa.x, xa.y, xa.z, xa.w, xb.x, xb.y, xb.z, xb.w};

        // W as float4 units: index ((j*P + p)*8 + d)*4 + og
        const float4* Wp = (const float4*)W + (size_t)p * 32 + og;

        float4 uh[J];
        float lg[J];
#pragma unroll
        for (int j = 0; j < J; ++j) {
            float4 wv[D];
#pragma unroll
            for (int d = 0; d < D; ++d)
                wv[d] = Wp[(size_t)j * ((size_t)P * 32) + d * 4];
            float4 u = make_float4(0.f, 0.f, 0.f, 0.f);
#pragma unroll
            for (int d = 0; d < D; ++d) {
                u.x = fmaf(xv[d], wv[d].x, u.x);
                u.y = fmaf(xv[d], wv[d].y, u.y);
                u.z = fmaf(xv[d], wv[d].z, u.z);
                u.w = fmaf(xv[d], wv[d].w, u.w);
            }
            uh[j] = u;
            if (!first) {
                const float4 vs4 = *(const float4*)&vs_s[bsub * VSTR + j * O + og * 4];
                float t = u.x * vs4.x;
                t = fmaf(u.y, vs4.y, t);
                t = fmaf(u.z, vs4.z, t);
                t = fmaf(u.w, vs4.w, t);
                lg[j] = quad_sum4(t);          // full sum over 16 o's
            }
        }

        if (first) {
            const float cj = 1.0f / (float)J;
#pragma unroll
            for (int j = 0; j < J; ++j) {
                acc[j].x = fmaf(cj, uh[j].x, acc[j].x);
                acc[j].y = fmaf(cj, uh[j].y, acc[j].y);
                acc[j].z = fmaf(cj, uh[j].z, acc[j].z);
                acc[j].w = fmaf(cj, uh[j].w, acc[j].w);
            }
        } else {
            float mx = lg[0];
#pragma unroll
            for (int j = 1; j < J; ++j) mx = fmaxf(mx, lg[j]);
            float e[J], Z = 0.f;
#pragma unroll
            for (int j = 0; j < J; ++j) { e[j] = __expf(lg[j] - mx); Z += e[j]; }
            const float rZ = __builtin_amdgcn_rcpf(Z);
#pragma unroll
            for (int j = 0; j < J; ++j) {
                const float cc = e[j] * rZ;
                acc[j].x = fmaf(cc, uh[j].x, acc[j].x);
                acc[j].y = fmaf(cc, uh[j].y, acc[j].y);
                acc[j].z = fmaf(cc, uh[j].z, acc[j].z);
                acc[j].w = fmaf(cc, uh[j].w, acc[j].w);
            }
        }
    }

    // fold the 4 psub p-chains (lane bits 2-3), og/bsub preserved
#pragma unroll
    for (int j = 0; j < J; ++j) {
        acc[j].x = psub_sum4(acc[j].x);
        acc[j].y = psub_sum4(acc[j].y);
        acc[j].z = psub_sum4(acc[j].z);
        acc[j].w = psub_sum4(acc[j].w);
    }

    // per-wave partials -> LDS (psub lanes write identical values to same addr: benign)
#pragma unroll
    for (int j = 0; j < J; ++j)
        *(float4*)&s_blk[wid][bsub * VSTR + j * O + og * 4] = acc[j];
    __syncthreads();

    // cross-wave sum + one atomicAdd per (b,j,o) per block (640/block)
    for (int t = tid; t < 4 * 160; t += 256) {
        const int bl = t / 160, r = t - bl * 160;
        const float v = s_blk[0][bl * VSTR + r] + s_blk[1][bl * VSTR + r]
                      + s_blk[2][bl * VSTR + r] + s_blk[3][bl * VSTR + r];
        atomicAdd(&s_acc[(bg * 4 + bl) * 160 + r], v);
    }
}

// v = squash(s); Vsum += v; zero s_acc for next pass; optionally emit v.
__global__ __launch_bounds__(64) void caps_squash(
    float* __restrict__ s_acc, float* __restrict__ Vsum,
    float* __restrict__ out, int write_out)
{
    const int row = blockIdx.x * 4 + (threadIdx.x >> 4); // 0..B*J-1
    const int o = threadIdx.x & 15;
    float s = s_acc[row * O + o];
    float sq = s * s;
#pragma unroll
    for (int m = 1; m < 16; m <<= 1) sq += __shfl_xor(sq, m, 64);
    const float v = s * (sqrtf(sq) / (1.f + sq));   // == |s|^2/((1+|s|^2)|s|)
    Vsum[row * O + o] += v;
    s_acc[row * O + o] = 0.f;
    if (write_out) out[row * O + o] = v;
}

__global__ __launch_bounds__(256) void caps_zero(float* __restrict__ ws)
{
    const int i = blockIdx.x * 256 + threadIdx.x;
    if (i < 2 * SJO) ws[i] = 0.f;   // s_acc + Vsum
}

extern "C" void kernel_launch(void* const* d_in, const int* in_sizes, int n_in,
                              void* d_out, int out_size, void* d_ws, size_t ws_size,
                              hipStream_t stream)
{
    const float* x = (const float*)d_in[0];
    const float* W = (const float*)d_in[1];
    float* out = (float*)d_out;

    float* s_acc = (float*)d_ws;          // SJO floats
    float* Vsum  = s_acc + SJO;           // SJO floats

    caps_zero<<<dim3((2 * SJO + 255) / 256), 256, 0, stream>>>(s_acc);

    for (int it = 0; it < 3; ++it) {
        caps_pass<<<dim3(NB), 256, 0, stream>>>(x, W, Vsum, s_acc, it == 0 ? 1 : 0);
        caps_squash<<<dim3(B * J / 4), 64, 0, stream>>>(s_acc, Vsum, out, it == 2 ? 1 : 0);
    }
}

// Round 7
// 271.109 us; speedup vs baseline: 1.9701x; 1.4328x over previous
//
#include <hip/hip_runtime.h>

typedef _Float16 half_t;
typedef half_t h2 __attribute__((ext_vector_type(2)));

#define J 10
#define P 16384
#define D 8
#define O 16
#define B 32

#define PTILE 16
#define NB ((P / PTILE) * 2)     // 2048 blocks (1024 p-tiles x 2 b-groups)
#define SJO (B * J * O)          // 5120

#define WT_PLS 2576              // bytes per pl slab of Wt: 10j*16o*8d*2B + 16 pad (bank stagger)
#define WT_PLH (WT_PLS / 2)      // 1288 halfs
#define XS_OFF (PTILE * WT_PLS)  // 41216 bytes
#define SMEM_BYTES (XS_OFF + PTILE * 16 * 16)  // + xs (16pl*16b*16B) = 45312
// epilogue s_blk aliases smem: 4*16*164*4 = 41984 B <= 45312  OK

// ---- DPP cross-lane helpers ----
template <int CTRL>
__device__ __forceinline__ float dpp_mov_f(float v) {
    return __int_as_float(__builtin_amdgcn_update_dpp(
        0, __float_as_int(v), CTRL, 0xF, 0xF, true));
}
// sum across a 16-lane row; result broadcast to all 16 lanes
__device__ __forceinline__ float row_sum16(float v) {
    v += dpp_mov_f<0xB1>(v);   // quad_perm xor 1
    v += dpp_mov_f<0x4E>(v);   // quad_perm xor 2
    v += dpp_mov_f<0x124>(v);  // row_ror:4
    v += dpp_mov_f<0x128>(v);  // row_ror:8
    return v;
}

// cvt_pkrtz returns __fp16x2; bit-cast to our _Float16x2
__device__ __forceinline__ h2 pkrtz(float a, float b) {
    return __builtin_bit_cast(h2, __builtin_amdgcn_cvt_pkrtz(a, b));
}

union U4H { uint4 u; h2 h[4]; };
union U1H { unsigned u; h2 h; };

// One routing pass. Grid: 1024 p-tiles x 2 b-groups (16 b each), swizzled so
// both bg's of a p-tile land on the same XCD. Block stages W-tile fp32->fp16
// into LDS [pl][j][o][d] with dense dwordx4 reads (kills the TA bottleneck),
// then computes with ds_read_b128 + v_dot2_f32_f16.
// Lane = (o:16, bsub:4); bc loop x4 covers 16 b; u_hat packed fp16 so each
// wv LDS read is amortized over 4 batches without register blowup.
__global__ __launch_bounds__(256, 3) void caps_pass(
    const float* __restrict__ x, const float* __restrict__ W,
    const unsigned* __restrict__ vs16, float* __restrict__ s_acc, int first)
{
    __shared__ char smem[SMEM_BYTES];
    half_t* Wt = (half_t*)smem;
    half_t* xs = (half_t*)(smem + XS_OFF);
    float* s_blk = (float*)smem;   // aliased after compute

    const int tid = threadIdx.x;
    const int i = blockIdx.x;
    const int bg = (i >> 3) & 1;
    const int pt = (i & 7) | ((i >> 4) << 3);   // XCD-swizzle: i and i+8 share pt
    const int p0 = pt * PTILE;

    // ---- stage W tile: fp32 [j][p][d][o] -> fp16 LDS [pl][j][o][d] ----
#pragma unroll
    for (int k = 0; k < 2; ++k) {
        const int idx = k * 256 + tid;               // 512 float4s per j-chunk
        const int o4 = idx & 3, d = (idx >> 2) & 7, pl = idx >> 5;
        const float* src = W + (size_t)p0 * (D * O) + (size_t)idx * 4;
        half_t* dst = Wt + pl * WT_PLH + (o4 * 4) * 8 + d;
        for (int j = 0; j < J; ++j) {
            float4 f = *(const float4*)(src + (size_t)j * P * (D * O));
            half_t* dj = dst + j * 128;
            dj[0]  = (half_t)f.x;
            dj[8]  = (half_t)f.y;
            dj[16] = (half_t)f.z;
            dj[24] = (half_t)f.w;
        }
    }
    // ---- stage x tile: fp32 -> fp16 LDS [pl][bl][d] ----
    {
        const int bl = tid >> 4, pl = tid & 15;
        const float4* xp = (const float4*)(x + ((size_t)(bg * 16 + bl) * P + p0 + pl) * D);
        float4 a = xp[0], c = xp[1];
        U4H pk;
        pk.h[0] = pkrtz(a.x, a.y);
        pk.h[1] = pkrtz(a.z, a.w);
        pk.h[2] = pkrtz(c.x, c.y);
        pk.h[3] = pkrtz(c.z, c.w);
        *(uint4*)(xs + (size_t)(pl * 16 + bl) * 8) = pk.u;
    }

    const int o = tid & 15, bsub = (tid >> 4) & 3, wid = tid >> 6;

    // Vsum packed fp16 (written by squash), per-lane registers
    h2 vsp[4][5];
    if (!first) {
#pragma unroll
        for (int bc = 0; bc < 4; ++bc) {
            const int b = bg * 16 + bc * 4 + bsub;
            const unsigned* src = vs16 + ((size_t)b * 16 + o) * 8;
            U4H q4; q4.u = *(const uint4*)src;
            U1H q1; q1.u = src[4];
            vsp[bc][0] = q4.h[0]; vsp[bc][1] = q4.h[1];
            vsp[bc][2] = q4.h[2]; vsp[bc][3] = q4.h[3];
            vsp[bc][4] = q1.h;
        }
    }
    __syncthreads();

    float acc[4][J];
#pragma unroll
    for (int bc = 0; bc < 4; ++bc)
#pragma unroll
        for (int j = 0; j < J; ++j) acc[bc][j] = 0.f;

#pragma unroll 1
    for (int pi = 0; pi < 4; ++pi) {
        const int pl = wid * 4 + pi;

        U4H xf[4];
#pragma unroll
        for (int bc = 0; bc < 4; ++bc)
            xf[bc].u = *(const uint4*)(xs + (size_t)(pl * 16 + bc * 4 + bsub) * 8);

        h2 uh_pk[2][J];
#pragma unroll
        for (int jh = 0; jh < 2; ++jh) {
            U4H wv[5];
#pragma unroll
            for (int j5 = 0; j5 < 5; ++j5)
                wv[j5].u = *(const uint4*)(Wt + (size_t)pl * WT_PLH
                                           + ((jh * 5 + j5) * 16 + o) * 8);
#pragma unroll
            for (int j5 = 0; j5 < 5; ++j5) {
                const int j = jh * 5 + j5;
                float u[4];
#pragma unroll
                for (int bc = 0; bc < 4; ++bc) {
                    float s = 0.f;
#pragma unroll
                    for (int dq = 0; dq < 4; ++dq)
                        s = __builtin_amdgcn_fdot2(wv[j5].h[dq], xf[bc].h[dq], s, false);
                    u[bc] = s;
                }
                if (first) {
#pragma unroll
                    for (int bc = 0; bc < 4; ++bc)
                        acc[bc][j] = fmaf(0.1f, u[bc], acc[bc][j]);
                } else {
                    uh_pk[0][j] = pkrtz(u[0], u[1]);
                    uh_pk[1][j] = pkrtz(u[2], u[3]);
                }
            }
        }

        if (!first) {
#pragma unroll
            for (int bc = 0; bc < 4; ++bc) {
                float uhf[J], lg[J];
#pragma unroll
                for (int j = 0; j < J; ++j) {
                    uhf[j] = (float)uh_pk[bc >> 1][j][bc & 1];
                    lg[j] = row_sum16(uhf[j] * (float)vsp[bc][j >> 1][j & 1]);
                }
                // max-free softmax: |lg| <~ 35 -> exp safe in fp32
                float e[J], Z = 0.f;
#pragma unroll
                for (int j = 0; j < J; ++j) { e[j] = __expf(lg[j]); Z += e[j]; }
                const float rZ = __builtin_amdgcn_rcpf(Z);
#pragma unroll
                for (int j = 0; j < J; ++j)
                    acc[bc][j] = fmaf(e[j] * rZ, uhf[j], acc[bc][j]);
            }
        }
    }

    // ---- epilogue: per-wave partials -> LDS (aliases Wt/xs) -> atomics ----
    __syncthreads();
#pragma unroll
    for (int bc = 0; bc < 4; ++bc) {
        const int bl = bc * 4 + bsub;
#pragma unroll
        for (int j = 0; j < J; ++j)
            s_blk[(wid * 16 + bl) * 164 + j * 16 + o] = acc[bc][j];
    }
    __syncthreads();
    for (int t = tid; t < 16 * 160; t += 256) {
        const int bl = t / 160, r = t - bl * 160;
        const float v = s_blk[bl * 164 + r] + s_blk[(16 + bl) * 164 + r]
                      + s_blk[(32 + bl) * 164 + r] + s_blk[(48 + bl) * 164 + r];
        atomicAdd(&s_acc[(bg * 16 + bl) * 160 + r], v);
    }
}

// v = squash(s); Vsum += v; emit vs16 (packed fp16, layout [b][o][j-pair]);
// zero s_acc; optionally emit v. One block per b: lane=(o:16, j:16, j<10 active).
__global__ __launch_bounds__(256) void caps_squash(
    float* __restrict__ s_acc, float* __restrict__ Vsum,
    unsigned* __restrict__ vs16, float* __restrict__ out, int write_out)
{
    const int b = blockIdx.x;
    const int o = threadIdx.x & 15;
    const int j = threadIdx.x >> 4;
    const bool act = j < J;
    const int idx = (b * J + (act ? j : 0)) * O + o;
    float s = act ? s_acc[idx] : 0.f;
    const float sq = row_sum16(s * s);
    float vnew = 0.f;
    if (act) {
        const float scale = sqrtf(sq) / (1.f + sq);   // |s|^2/((1+|s|^2)|s|)
        const float v = s * scale;
        vnew = Vsum[idx] + v;
        Vsum[idx] = vnew;
        s_acc[idx] = 0.f;
        if (write_out) out[idx] = v;
    }
    const float vpart = __shfl_xor(vnew, 16, 64);     // partner j^1
    if (act && !(j & 1)) {
        U1H t; t.h = pkrtz(vnew, vpart);
        vs16[((size_t)b * 16 + o) * 8 + (j >> 1)] = t.u;
    }
}

__global__ __launch_bounds__(256) void caps_zero(float* __restrict__ ws)
{
    const int i = blockIdx.x * 256 + threadIdx.x;
    if (i < 2 * SJO) ws[i] = 0.f;   // s_acc + Vsum
}

extern "C" void kernel_launch(void* const* d_in, const int* in_sizes, int n_in,
                              void* d_out, int out_size, void* d_ws, size_t ws_size,
                              hipStream_t stream)
{
    const float* x = (const float*)d_in[0];
    const float* W = (const float*)d_in[1];
    float* out = (float*)d_out;

    float* s_acc = (float*)d_ws;               // SJO floats
    float* Vsum  = s_acc + SJO;                // SJO floats
    unsigned* vs16 = (unsigned*)(Vsum + SJO);  // B*16*8 dwords (16 KB)

    caps_zero<<<dim3(40), 256, 0, stream>>>(s_acc);

    for (int it = 0; it < 3; ++it) {
        caps_pass<<<dim3(NB), 256, 0, stream>>>(x, W, vs16, s_acc, it == 0 ? 1 : 0);
        caps_squash<<<dim3(B), 256, 0, stream>>>(s_acc, Vsum, vs16, out, it == 2 ? 1 : 0);
    }
}